// Round 7
// baseline (419.613 us; speedup 1.0000x reference)
//
#include <hip/hip_runtime.h>
#include <hip/hip_bf16.h>

#define BB 64
#define SS 8192
#define DD 128
#define NCHUNK 8    // chunks per batch
#define CHROWS 1024 // rows per chunk
#define NTILE 16    // 64-row tiles per chunk

typedef __attribute__((ext_vector_type(8))) short bf16x8;
typedef __attribute__((ext_vector_type(4))) float f32x4;

// swizzled slot within a (w,kk) 128-slot region; 8-byte units
#define SWZ(c, qd) ((qd) * 16 + ((c) ^ (2 * (qd))))

__device__ __forceinline__ unsigned pk2(float x, float y) {
    __hip_bfloat162 h = __float22bfloat162_rn(make_float2(x, y));
    union { __hip_bfloat162 h2; unsigned u; } cv;
    cv.h2 = h;
    return cv.u;
}

__device__ __forceinline__ float bflo(unsigned p) { return __uint_as_float(p << 16); }
__device__ __forceinline__ float bfhi(unsigned p) { return __uint_as_float(p & 0xffff0000u); }

__device__ __forceinline__ float tanh_fast(float x) {
    float e = __expf(2.f * x);
    return 1.f - 2.f / (e + 1.f);
}

// LDS-visibility barrier that does NOT drain outstanding global loads
// (unlike __syncthreads, which forces s_waitcnt vmcnt(0) before s_barrier).
__device__ __forceinline__ void lds_barrier() {
    asm volatile("s_waitcnt lgkmcnt(0)" ::: "memory");
    __builtin_amdgcn_s_barrier();
    asm volatile("" ::: "memory");
}

// ---------------- K1: q = tanh(input @ W_dec^T + b_dec)
__global__ void qproj_kernel(const float* __restrict__ input,
                             const float* __restrict__ W_dec,
                             const float* __restrict__ b_dec,
                             float* __restrict__ q) {
    __shared__ float xin[DD];
    const int b = blockIdx.x, d = threadIdx.x;  // 128 threads
    xin[d] = input[b * DD + d];
    __syncthreads();
    const float4* wrow = (const float4*)(W_dec + (size_t)d * DD);
    float acc = 0.f;
#pragma unroll
    for (int k4 = 0; k4 < DD / 4; k4++) {
        float4 w = wrow[k4];
        float4 x = ((const float4*)xin)[k4];
        acc += w.x * x.x + w.y * x.y + w.z * x.z + w.w * x.w;
    }
    q[b * DD + d] = tanh_fast(acc + b_dec[d]);
}

// issue tile's global loads into register buffer R (8 x dwordx4, coalesced)
#define ISSUE(tile, R) do {                                          \
    const float4* tb_ = base + (size_t)(tile) * 2048;                \
    _Pragma("unroll")                                                \
    for (int i = 0; i < 8; i++) R[i] = tb_[t + 256 * i];             \
} while (0)

// pack register buffer R into Cl[buf]; keep bf16 pairs in P for the wsum.
// The counted vmcnt wait for R lands here -- ~1.5 tile-phases after issue.
#define PACK(buf, R) do {                                            \
    _Pragma("unroll")                                                \
    for (int i = 0; i < 8; i++) {                                    \
        int row_ = rg + 8 * i, w_ = row_ >> 4, c_ = row_ & 15;       \
        int a8_ = (w_ * 4 + ukk) * 128 + SWZ(c_, uqd) * 2 + uh;      \
        uint2 pk_;                                                   \
        pk_.x = pk2(R[i].x, R[i].y);                                 \
        pk_.y = pk2(R[i].z, R[i].w);                                 \
        P[i] = pk_;                                                  \
        *(uint2*)&Cl[buf][a8_ * 4] = pk_;                            \
    }                                                                \
} while (0)

// ---------------- K2: fused scores + online softmax + weighted ctx sum
// R2 skeleton (lockstep, double-buffered Cl, 2 barriers/tile) +
//  (a) raw-barrier main loop (no vmcnt(0) anywhere in the loop)  [R6, proven]
//  (b) 2-deep RA/RB register prefetch: tile t+2 issued at tile t  [R5 dataflow]
//  -> pack(t+1)'s counted vmcnt wait targets loads issued ~1.5 phases ago;
//     every wave keeps 8-16 loads outstanding across barriers.
__global__ __launch_bounds__(256, 2) void score_fused_kernel(
    const float* __restrict__ ctx,
    const float* __restrict__ W_enc,
    const float* __restrict__ b_enc,
    const float* __restrict__ q,
    float* __restrict__ scores,
    float* __restrict__ wcp,   // [512][128]
    float* __restrict__ Mp,    // [512]
    float* __restrict__ Tp) {  // [512]
    __shared__ __align__(16) short Wl[16384];     // 32 KB fragment-order W_enc
    __shared__ __align__(16) short Cl[2][8192];   // 2 x 16 KB swizzled bf16 ctx tile
    __shared__ float sw[64];
    __shared__ float4 red[256];

    const int t = threadIdx.x;

    // ---- stage W_enc: region (nt*4+kk), slot SWZ(col,qd), halves h=0/1
    const float4* W4 = (const float4*)W_enc;
    for (int c2 = t; c2 < 2048; c2 += 256) {
        int row = c2 >> 4, kc = c2 & 15;
        float4 f0 = W4[row * 32 + kc * 2];
        float4 f1 = W4[row * 32 + kc * 2 + 1];
        int nt = row >> 4, colw = row & 15, kk = kc >> 2, qd = kc & 3;
        int a8 = (nt * 4 + kk) * 128 + SWZ(colw, qd) * 2;
        uint4 u;
        u.x = pk2(f0.x, f0.y); u.y = pk2(f0.z, f0.w);
        u.z = pk2(f1.x, f1.y); u.w = pk2(f1.z, f1.w);
        *(uint4*)&Wl[a8 * 4] = u;
    }

    const int wv = t >> 6, lane = t & 63;
    const int col = lane & 15, quad = lane >> 4;
    const int b = blockIdx.x >> 3;
    const int chunk = blockIdx.x & 7;

    // per-thread piece coords for pack / weighted-sum
    const int u = t & 31, rg = t >> 5;
    const int ukk = u >> 3, uqd = (u >> 1) & 3, uh = u & 1;

    float qv[8], bv[8];
#pragma unroll
    for (int nt = 0; nt < 8; nt++) {
        qv[nt] = q[b * DD + nt * 16 + col];
        bv[nt] = b_enc[nt * 16 + col];
    }

    const float4* base = (const float4*)(ctx + ((size_t)b * SS + (size_t)chunk * CHROWS) * DD);

    float4 RA[8], RB[8];
    uint2 P[8];

    float Mrun = -INFINITY, Trun = 0.f;
    float4 acc4 = {0.f, 0.f, 0.f, 0.f};

    // MFMA + tanh/dot epilogue + score write for tile `it` from Cl[cur]
    // (R2's proven compute shape: all 32 MFMAs issue, then epilogue)
    auto compute_tile = [&](int it, int cur) {
        bf16x8 a[4];
#pragma unroll
        for (int kk = 0; kk < 4; kk++) {
            int a8 = (wv * 4 + kk) * 128 + SWZ(col, quad) * 2;
            a[kk] = *(const bf16x8*)&Cl[cur][a8 * 4];
        }
        f32x4 acc[8];
#pragma unroll
        for (int nt = 0; nt < 8; nt++) {
            f32x4 c = {0.f, 0.f, 0.f, 0.f};
#pragma unroll
            for (int kk = 0; kk < 4; kk++) {
                int a8 = (nt * 4 + kk) * 128 + SWZ(col, quad) * 2;
                bf16x8 bf = *(const bf16x8*)&Wl[a8 * 4];
                c = __builtin_amdgcn_mfma_f32_16x16x32_bf16(a[kk], bf, c, 0, 0, 0);
            }
            acc[nt] = c;
        }
#pragma unroll
        for (int r = 0; r < 4; r++) {
            float v = 0.f;
#pragma unroll
            for (int nt = 0; nt < 8; nt++)
                v += tanh_fast(acc[nt][r] + bv[nt]) * qv[nt];
            v += __shfl_xor(v, 1);
            v += __shfl_xor(v, 2);
            v += __shfl_xor(v, 4);
            v += __shfl_xor(v, 8);
            if (col == 0) {
                int lrow = wv * 16 + quad * 4 + r;
                sw[lrow] = v;
                scores[(size_t)b * SS + (size_t)chunk * CHROWS + it * 64 + lrow] = v;
            }
        }
    };

    // online softmax over this tile's 64 rows + weighted ctx accumulation
    // from the pack-time bf16 registers P (bit-identical to the LDS values)
    auto softmax_wsum = [&]() {
        float sv = sw[lane];
        float m = sv;
#pragma unroll
        for (int off = 1; off < 64; off <<= 1) m = fmaxf(m, __shfl_xor(m, off));
        float Mnew = fmaxf(Mrun, m);
        float alpha = __expf(Mrun - Mnew);
        float wlane = __expf(sv - Mnew);
        float ts = wlane;
#pragma unroll
        for (int off = 1; off < 64; off <<= 1) ts += __shfl_xor(ts, off);
        Trun = Trun * alpha + ts;
        Mrun = Mnew;

        acc4.x *= alpha; acc4.y *= alpha; acc4.z *= alpha; acc4.w *= alpha;
#pragma unroll
        for (int i = 0; i < 8; i++) {
            int row = rg + 8 * i;
            uint2 pk = P[i];
            float wi = __shfl(wlane, row);
            acc4.x += wi * bflo(pk.x);
            acc4.y += wi * bfhi(pk.x);
            acc4.z += wi * bflo(pk.y);
            acc4.w += wi * bfhi(pk.y);
        }
    };

    // prologue: tiles 0,1 in flight; pack tile 0 (counted wait on RA only;
    // RB stays in flight across the barrier)
    ISSUE(0, RA);
    ISSUE(1, RB);
    PACK(0, RA);
    lds_barrier();  // Wl + Cl[0] visible

    for (int it2 = 0; it2 < NTILE / 2; ++it2) {
        const int T = 2 * it2;

        // ---- tile T (even, Cl[0], reg parity A); issue T+2 -> RA
        if (T + 2 < NTILE) ISSUE(T + 2, RA);
        compute_tile(T, 0);
        lds_barrier();          // A: sw visible; Cl[0] frag reads done
        softmax_wsum();         // P = tile T
        PACK(1, RB);            // tile T+1 -> Cl[1], P (RB issued 2 phases ago)
        lds_barrier();          // B: Cl[1] ready; sw reads done

        // ---- tile T+1 (odd, Cl[1], reg parity B); issue T+3 -> RB
        if (T + 3 < NTILE) ISSUE(T + 3, RB);
        compute_tile(T + 1, 1);
        lds_barrier();          // A
        softmax_wsum();         // P = tile T+1
        if (T + 2 < NTILE) PACK(0, RA);  // tile T+2 -> Cl[0], P
        lds_barrier();          // B
    }

    // ---- block reduce: thread t holds dims [4u,4u+4) over row-group rg
    red[t] = acc4;
    __syncthreads();
    if (t < 32) {
        float4 s = red[t];
#pragma unroll
        for (int k = 1; k < 8; k++) {
            float4 p = red[t + 32 * k];
            s.x += p.x; s.y += p.y; s.z += p.z; s.w += p.w;
        }
        *(float4*)&wcp[(size_t)blockIdx.x * DD + 4 * t] = s;
    }
    if (t == 0) {
        Mp[blockIdx.x] = Mrun;
        Tp[blockIdx.x] = Trun;
    }
}

// ---------------- K3: combine 8 per-block partials per batch + fused out proj
__global__ void combine_out_kernel(const float* __restrict__ wcp,
                                   const float* __restrict__ Mp,
                                   const float* __restrict__ Tp,
                                   const float* __restrict__ q,
                                   const float* __restrict__ W_out,
                                   float* __restrict__ h,
                                   float* __restrict__ Ms,
                                   float* __restrict__ Tinv) {
    __shared__ float cat[2 * DD];
    const int b = blockIdx.x, d = threadIdx.x;  // 128 threads
    float M = -INFINITY;
#pragma unroll
    for (int j = 0; j < NCHUNK; j++) M = fmaxf(M, Mp[b * NCHUNK + j]);
    float T = 0.f, acc = 0.f;
#pragma unroll
    for (int j = 0; j < NCHUNK; j++) {
        float e = __expf(Mp[b * NCHUNK + j] - M);
        T += Tp[b * NCHUNK + j] * e;
        acc += wcp[(size_t)(b * NCHUNK + j) * DD + d] * e;
    }
    float ti = 1.f / T;
    cat[d] = acc * ti;          // weighted_context
    cat[DD + d] = q[b * DD + d];
    if (d == 0) { Ms[b] = M; Tinv[b] = ti; }
    __syncthreads();
    const float4* wrow = (const float4*)(W_out + (size_t)d * 2 * DD);
    float a2 = 0.f;
#pragma unroll
    for (int k4 = 0; k4 < 2 * DD / 4; k4++) {
        float4 w = wrow[k4];
        float4 x = ((const float4*)cat)[k4];
        a2 += w.x * x.x + w.y * x.y + w.z * x.z + w.w * x.w;
    }
    h[b * DD + d] = tanh_fast(a2);
}

// ---------------- K4: attn = exp(scores - M)/T
__global__ __launch_bounds__(512) void attnfin_kernel(const float* __restrict__ scores,
                                                      const float* __restrict__ Ms,
                                                      const float* __restrict__ Tinv,
                                                      float* __restrict__ attn) {
    const int b = blockIdx.x >> 2, seg = blockIdx.x & 3;
    const float M = Ms[b], ti = Tinv[b];
    const float4* s4 = (const float4*)(scores + (size_t)b * SS) + seg * 512;
    float4* a4 = (float4*)(attn + (size_t)b * SS) + seg * 512;
    float4 v = s4[threadIdx.x];
    v.x = __expf(v.x - M) * ti;
    v.y = __expf(v.y - M) * ti;
    v.z = __expf(v.z - M) * ti;
    v.w = __expf(v.w - M) * ti;
    a4[threadIdx.x] = v;
}

extern "C" void kernel_launch(void* const* d_in, const int* in_sizes, int n_in,
                              void* d_out, int out_size, void* d_ws, size_t ws_size,
                              hipStream_t stream) {
    const float* input = (const float*)d_in[0];
    const float* ctx   = (const float*)d_in[1];
    const float* W_enc = (const float*)d_in[2];
    const float* b_enc = (const float*)d_in[3];
    const float* W_dec = (const float*)d_in[4];
    const float* b_dec = (const float*)d_in[5];
    const float* W_out = (const float*)d_in[6];

    float* h    = (float*)d_out;            // [B, D]
    float* attn = (float*)d_out + BB * DD;  // [B, S]

    float* ws     = (float*)d_ws;
    float* q      = ws;                       // 8192
    float* scores = ws + 8192;                // 524288 raw scores
    float* wcp    = scores + 524288;          // 512*128 partials
    float* Mp     = wcp + 512 * DD;           // 512
    float* Tp     = Mp + 512;                 // 512
    float* Ms     = Tp + 512;                 // 64
    float* Tinv   = Ms + 64;                  // 64

    qproj_kernel<<<BB, DD, 0, stream>>>(input, W_dec, b_dec, q);
    score_fused_kernel<<<BB * NCHUNK, 256, 0, stream>>>(ctx, W_enc, b_enc, q,
                                                        scores, wcp, Mp, Tp);
    combine_out_kernel<<<BB, DD, 0, stream>>>(wcp, Mp, Tp, q, W_out, h, Ms, Tinv);
    attnfin_kernel<<<BB * 4, 512, 0, stream>>>(scores, Ms, Tinv, attn);
}

// Round 8
// 413.684 us; speedup vs baseline: 1.0143x; 1.0143x over previous
//
#include <hip/hip_runtime.h>
#include <hip/hip_bf16.h>

#define BB 64
#define SS 8192
#define DD 128
#define NCHUNK 12   // chunks per batch (768 blocks = 3/CU, all co-resident)
#define NTTOT 128   // 64-row tiles per batch

typedef __attribute__((ext_vector_type(8))) short bf16x8;
typedef __attribute__((ext_vector_type(4))) float f32x4;

// swizzled slot within a (w,kk) 128-slot region; 8-byte units
#define SWZ(c, qd) ((qd) * 16 + ((c) ^ (2 * (qd))))

__device__ __forceinline__ unsigned pk2(float x, float y) {
    __hip_bfloat162 h = __float22bfloat162_rn(make_float2(x, y));
    union { __hip_bfloat162 h2; unsigned u; } cv;
    cv.h2 = h;
    return cv.u;
}

__device__ __forceinline__ float bflo(unsigned p) { return __uint_as_float(p << 16); }
__device__ __forceinline__ float bfhi(unsigned p) { return __uint_as_float(p & 0xffff0000u); }

__device__ __forceinline__ float tanh_fast(float x) {
    float e = __expf(2.f * x);
    return 1.f - 2.f / (e + 1.f);
}

// LDS-visibility barrier that does NOT drain outstanding global loads
// (unlike __syncthreads, which forces s_waitcnt vmcnt(0) before s_barrier).
__device__ __forceinline__ void lds_barrier() {
    asm volatile("s_waitcnt lgkmcnt(0)" ::: "memory");
    __builtin_amdgcn_s_barrier();
    asm volatile("" ::: "memory");
}

// ---------------- K1: q = tanh(input @ W_dec^T + b_dec)
__global__ void qproj_kernel(const float* __restrict__ input,
                             const float* __restrict__ W_dec,
                             const float* __restrict__ b_dec,
                             float* __restrict__ q) {
    __shared__ float xin[DD];
    const int b = blockIdx.x, d = threadIdx.x;  // 128 threads
    xin[d] = input[b * DD + d];
    __syncthreads();
    const float4* wrow = (const float4*)(W_dec + (size_t)d * DD);
    float acc = 0.f;
#pragma unroll
    for (int k4 = 0; k4 < DD / 4; k4++) {
        float4 w = wrow[k4];
        float4 x = ((const float4*)xin)[k4];
        acc += w.x * x.x + w.y * x.y + w.z * x.z + w.w * x.w;
    }
    q[b * DD + d] = tanh_fast(acc + b_dec[d]);
}

// ---------------- K2: fused scores + online softmax + weighted ctx sum
// R6 structure (lockstep, raw barriers, P-register wsum, 1-deep prefetch)
// with SINGLE Cl buffer (P-trick makes the 2nd buffer dead weight):
// LDS 69->50 KB -> 3 independent blocks/CU. Different per-block tile
// counts (10/11) desynchronize the blocks' barrier phases -> the CU's
// HBM issue window stays busy across all three blocks.
__global__ __launch_bounds__(256, 3) void score_fused_kernel(
    const float* __restrict__ ctx,
    const float* __restrict__ W_enc,
    const float* __restrict__ b_enc,
    const float* __restrict__ q,
    float* __restrict__ scores,
    float* __restrict__ wcp,   // [768][128]
    float* __restrict__ Mp,    // [768]
    float* __restrict__ Tp) {  // [768]
    __shared__ __align__(16) short Wl[16384];   // 32 KB fragment-order W_enc
    __shared__ __align__(16) short Cl[8192];    // 16 KB swizzled bf16 ctx tile
    __shared__ float sw[64];
    __shared__ float4 red[128];                 // 2 KB (wave-pre-reduced)

    const int t = threadIdx.x;

    // ---- stage W_enc: region (nt*4+kk), slot SWZ(col,qd), halves h=0/1
    const float4* W4 = (const float4*)W_enc;
    for (int c2 = t; c2 < 2048; c2 += 256) {
        int row = c2 >> 4, kc = c2 & 15;
        float4 f0 = W4[row * 32 + kc * 2];
        float4 f1 = W4[row * 32 + kc * 2 + 1];
        int nt = row >> 4, colw = row & 15, kk = kc >> 2, qd = kc & 3;
        int a8 = (nt * 4 + kk) * 128 + SWZ(colw, qd) * 2;
        uint4 u;
        u.x = pk2(f0.x, f0.y); u.y = pk2(f0.z, f0.w);
        u.z = pk2(f1.x, f1.y); u.w = pk2(f1.z, f1.w);
        *(uint4*)&Wl[a8 * 4] = u;
    }

    const int wv = t >> 6, lane = t & 63;
    const int col = lane & 15, quad = lane >> 4;

    const int bidx = blockIdx.x;
    const int b = bidx / NCHUNK;
    const int chunk = bidx - b * NCHUNK;
    const int tstart = (chunk * NTTOT) / NCHUNK;        // 10/11-tile split
    const int tend = ((chunk + 1) * NTTOT) / NCHUNK;
    const int ntiles = tend - tstart;

    // per-thread piece coords for pack / weighted-sum
    const int u = t & 31, rg = t >> 5;
    const int ukk = u >> 3, uqd = (u >> 1) & 3, uh = u & 1;

    float qv[8], bv[8];
#pragma unroll
    for (int nt = 0; nt < 8; nt++) {
        qv[nt] = q[b * DD + nt * 16 + col];
        bv[nt] = b_enc[nt * 16 + col];
    }

    const float4* base = (const float4*)(ctx + ((size_t)b * SS + (size_t)tstart * 64) * DD);

    float4 R[8];
    uint2 P[8];
    // pack R -> Cl at this thread's 8 (row, piece) slots; keep pairs in P
    auto pack_tile = [&]() {
#pragma unroll
        for (int i = 0; i < 8; i++) {
            int row = rg + 8 * i, w = row >> 4, c = row & 15;
            int a8 = (w * 4 + ukk) * 128 + SWZ(c, uqd) * 2 + uh;
            uint2 pk;
            pk.x = pk2(R[i].x, R[i].y);
            pk.y = pk2(R[i].z, R[i].w);
            P[i] = pk;
            *(uint2*)&Cl[a8 * 4] = pk;
        }
    };

    // prologue: tile 0
#pragma unroll
    for (int i = 0; i < 8; i++) R[i] = base[t + 256 * i];
    pack_tile();
    __syncthreads();  // Wl + Cl(tile 0) ready

    float Mrun = -INFINITY, Trun = 0.f;
    float4 acc4 = {0.f, 0.f, 0.f, 0.f};

    for (int it = 0; it < ntiles; ++it) {
        // issue next-tile loads; in flight across both barriers (raw barriers
        // never drain vmcnt; counted wait lands at next pack, a phase later)
        if (it < ntiles - 1) {
            const float4* tb = base + (size_t)(it + 1) * 2048;
#pragma unroll
            for (int i = 0; i < 8; i++) R[i] = tb[t + 256 * i];
        }

        // ---- MFMA from swizzled Cl / Wl (proven compute shape)
        bf16x8 a[4];
#pragma unroll
        for (int kk = 0; kk < 4; kk++) {
            int a8 = (wv * 4 + kk) * 128 + SWZ(col, quad) * 2;
            a[kk] = *(const bf16x8*)&Cl[a8 * 4];
        }
        f32x4 acc[8];
#pragma unroll
        for (int nt = 0; nt < 8; nt++) {
            f32x4 c = {0.f, 0.f, 0.f, 0.f};
#pragma unroll
            for (int kk = 0; kk < 4; kk++) {
                int a8 = (nt * 4 + kk) * 128 + SWZ(col, quad) * 2;
                bf16x8 bf = *(const bf16x8*)&Wl[a8 * 4];
                c = __builtin_amdgcn_mfma_f32_16x16x32_bf16(a[kk], bf, c, 0, 0, 0);
            }
            acc[nt] = c;
        }

        // ---- epilogue: tanh, dot q, col-reduce, write sw + raw scores
#pragma unroll
        for (int r = 0; r < 4; r++) {
            float v = 0.f;
#pragma unroll
            for (int nt = 0; nt < 8; nt++)
                v += tanh_fast(acc[nt][r] + bv[nt]) * qv[nt];
            v += __shfl_xor(v, 1);
            v += __shfl_xor(v, 2);
            v += __shfl_xor(v, 4);
            v += __shfl_xor(v, 8);
            if (col == 0) {
                int lrow = wv * 16 + quad * 4 + r;
                sw[lrow] = v;
                scores[(size_t)b * SS + (size_t)(tstart + it) * 64 + lrow] = v;
            }
        }
        lds_barrier();  // A: sw visible; ALL waves' Cl frag reads done

        // ---- per-wave (redundant) online softmax over this tile's 64 rows
        float sv = sw[lane];
        float m = sv;
#pragma unroll
        for (int off = 1; off < 64; off <<= 1) m = fmaxf(m, __shfl_xor(m, off));
        float Mnew = fmaxf(Mrun, m);
        float alpha = __expf(Mrun - Mnew);
        float wlane = __expf(sv - Mnew);
        float ts = wlane;
#pragma unroll
        for (int off = 1; off < 64; off <<= 1) ts += __shfl_xor(ts, off);
        Trun = Trun * alpha + ts;
        Mrun = Mnew;

        // ---- weighted ctx accumulation from pack-time registers (tile it)
        acc4.x *= alpha; acc4.y *= alpha; acc4.z *= alpha; acc4.w *= alpha;
#pragma unroll
        for (int i = 0; i < 8; i++) {
            int row = rg + 8 * i;
            uint2 pk = P[i];
            float wi = __shfl(wlane, row);
            acc4.x += wi * bflo(pk.x);
            acc4.y += wi * bfhi(pk.x);
            acc4.z += wi * bflo(pk.y);
            acc4.w += wi * bfhi(pk.y);
        }

        // pack next tile into the SAME buffer (reads completed at barrier A)
        if (it < ntiles - 1) pack_tile();

        lds_barrier();  // B: Cl(next) ready; sw reads done
    }

    // ---- block reduce (wave pre-reduce over row-group parity first)
    acc4.x += __shfl_xor(acc4.x, 32);
    acc4.y += __shfl_xor(acc4.y, 32);
    acc4.z += __shfl_xor(acc4.z, 32);
    acc4.w += __shfl_xor(acc4.w, 32);
    if (lane < 32) red[wv * 32 + lane] = acc4;
    __syncthreads();
    if (t < 32) {
        float4 p0 = red[t], p1 = red[32 + t], p2 = red[64 + t], p3 = red[96 + t];
        float4 s;
        s.x = p0.x + p1.x + p2.x + p3.x;
        s.y = p0.y + p1.y + p2.y + p3.y;
        s.z = p0.z + p1.z + p2.z + p3.z;
        s.w = p0.w + p1.w + p2.w + p3.w;
        *(float4*)&wcp[(size_t)bidx * DD + 4 * t] = s;
    }
    if (t == 0) {
        Mp[bidx] = Mrun;
        Tp[bidx] = Trun;
    }
}

// ---------------- K3: combine 12 per-block partials per batch + fused out proj
__global__ void combine_out_kernel(const float* __restrict__ wcp,
                                   const float* __restrict__ Mp,
                                   const float* __restrict__ Tp,
                                   const float* __restrict__ q,
                                   const float* __restrict__ W_out,
                                   float* __restrict__ h,
                                   float* __restrict__ Ms,
                                   float* __restrict__ Tinv) {
    __shared__ float cat[2 * DD];
    const int b = blockIdx.x, d = threadIdx.x;  // 128 threads
    float M = -INFINITY;
#pragma unroll
    for (int j = 0; j < NCHUNK; j++) M = fmaxf(M, Mp[b * NCHUNK + j]);
    float T = 0.f, acc = 0.f;
#pragma unroll
    for (int j = 0; j < NCHUNK; j++) {
        float e = __expf(Mp[b * NCHUNK + j] - M);
        T += Tp[b * NCHUNK + j] * e;
        acc += wcp[(size_t)(b * NCHUNK + j) * DD + d] * e;
    }
    float ti = 1.f / T;
    cat[d] = acc * ti;          // weighted_context
    cat[DD + d] = q[b * DD + d];
    if (d == 0) { Ms[b] = M; Tinv[b] = ti; }
    __syncthreads();
    const float4* wrow = (const float4*)(W_out + (size_t)d * 2 * DD);
    float a2 = 0.f;
#pragma unroll
    for (int k4 = 0; k4 < 2 * DD / 4; k4++) {
        float4 w = wrow[k4];
        float4 x = ((const float4*)cat)[k4];
        a2 += w.x * x.x + w.y * x.y + w.z * x.z + w.w * x.w;
    }
    h[b * DD + d] = tanh_fast(a2);
}

// ---------------- K4: attn = exp(scores - M)/T
__global__ __launch_bounds__(512) void attnfin_kernel(const float* __restrict__ scores,
                                                      const float* __restrict__ Ms,
                                                      const float* __restrict__ Tinv,
                                                      float* __restrict__ attn) {
    const int b = blockIdx.x >> 2, seg = blockIdx.x & 3;
    const float M = Ms[b], ti = Tinv[b];
    const float4* s4 = (const float4*)(scores + (size_t)b * SS) + seg * 512;
    float4* a4 = (float4*)(attn + (size_t)b * SS) + seg * 512;
    float4 v = s4[threadIdx.x];
    v.x = __expf(v.x - M) * ti;
    v.y = __expf(v.y - M) * ti;
    v.z = __expf(v.z - M) * ti;
    v.w = __expf(v.w - M) * ti;
    a4[threadIdx.x] = v;
}

extern "C" void kernel_launch(void* const* d_in, const int* in_sizes, int n_in,
                              void* d_out, int out_size, void* d_ws, size_t ws_size,
                              hipStream_t stream) {
    const float* input = (const float*)d_in[0];
    const float* ctx   = (const float*)d_in[1];
    const float* W_enc = (const float*)d_in[2];
    const float* b_enc = (const float*)d_in[3];
    const float* W_dec = (const float*)d_in[4];
    const float* b_dec = (const float*)d_in[5];
    const float* W_out = (const float*)d_in[6];

    float* h    = (float*)d_out;            // [B, D]
    float* attn = (float*)d_out + BB * DD;  // [B, S]

    float* ws     = (float*)d_ws;
    float* q      = ws;                       // 8192
    float* scores = ws + 8192;                // 524288 raw scores
    float* wcp    = scores + 524288;          // 768*128 partials
    float* Mp     = wcp + 768 * DD;           // 768
    float* Tp     = Mp + 768;                 // 768
    float* Ms     = Tp + 768;                 // 64
    float* Tinv   = Ms + 64;                  // 64

    qproj_kernel<<<BB, DD, 0, stream>>>(input, W_dec, b_dec, q);
    score_fused_kernel<<<BB * NCHUNK, 256, 0, stream>>>(ctx, W_enc, b_enc, q,
                                                        scores, wcp, Mp, Tp);
    combine_out_kernel<<<BB, DD, 0, stream>>>(wcp, Mp, Tp, q, W_out, h, Ms, Tinv);
    attnfin_kernel<<<BB * 4, 512, 0, stream>>>(scores, Ms, Tinv, attn);
}

// Round 9
// 401.915 us; speedup vs baseline: 1.0440x; 1.0293x over previous
//
#include <hip/hip_runtime.h>
#include <hip/hip_bf16.h>

#define BB 64
#define SS 8192
#define DD 128
#define NCHUNK 8    // chunks per batch
#define CHROWS 1024 // rows per chunk
#define NTILE 16    // 64-row tiles per chunk

typedef __attribute__((ext_vector_type(8))) short bf16x8;
typedef __attribute__((ext_vector_type(4))) float f32x4;

// swizzled slot within a (w,kk) 128-slot region; 8-byte units
#define SWZ(c, qd) ((qd) * 16 + ((c) ^ (2 * (qd))))

__device__ __forceinline__ unsigned pk2(float x, float y) {
    __hip_bfloat162 h = __float22bfloat162_rn(make_float2(x, y));
    union { __hip_bfloat162 h2; unsigned u; } cv;
    cv.h2 = h;
    return cv.u;
}

__device__ __forceinline__ float bflo(unsigned p) { return __uint_as_float(p << 16); }
__device__ __forceinline__ float bfhi(unsigned p) { return __uint_as_float(p & 0xffff0000u); }

__device__ __forceinline__ float tanh_fast(float x) {
    float e = __expf(2.f * x);
    return 1.f - 2.f / (e + 1.f);
}

// LDS-visibility barrier that does NOT drain outstanding global loads
// (unlike __syncthreads, which forces s_waitcnt vmcnt(0) before s_barrier).
__device__ __forceinline__ void lds_barrier() {
    asm volatile("s_waitcnt lgkmcnt(0)" ::: "memory");
    __builtin_amdgcn_s_barrier();
    asm volatile("" ::: "memory");
}

// ---------------- K2: fused qproj + scores + online softmax + weighted ctx
// Interior = R6's proven 400.7us structure, byte-identical:
// lockstep, double-buffered Cl, raw barriers, P-register wsum, 1-deep
// prefetch. New: q computed inline per block (same FP op order as the old
// qproj kernel -> bit-identical), overlapping W_enc staging AND tile-0 load
// latency; chunk-0 blocks write q for K3.
__global__ __launch_bounds__(256, 2) void score_fused_kernel(
    const float* __restrict__ ctx,
    const float* __restrict__ W_enc,
    const float* __restrict__ b_enc,
    const float* __restrict__ input,
    const float* __restrict__ W_dec,
    const float* __restrict__ b_dec,
    float* __restrict__ q,     // [64][128]   (written by chunk==0 blocks)
    float* __restrict__ scores,
    float* __restrict__ wcp,   // [512][128]
    float* __restrict__ Mp,    // [512]
    float* __restrict__ Tp) {  // [512]
    __shared__ __align__(16) short Wl[16384];     // 32 KB fragment-order W_enc
    __shared__ __align__(16) short Cl[2][8192];   // 2 x 16 KB swizzled bf16 ctx tile
    __shared__ float sw[64];
    __shared__ float4 red[256];
    __shared__ float xin[DD];
    __shared__ float qsh[DD];

    const int t = threadIdx.x;
    const int b = blockIdx.x >> 3;
    const int chunk = blockIdx.x & 7;

    // ---- prologue phase 1: xin, W_enc staging, tile-0 issue (all overlap)
    if (t < DD) xin[t] = input[b * DD + t];

    const float4* W4 = (const float4*)W_enc;
    for (int c2 = t; c2 < 2048; c2 += 256) {
        int row = c2 >> 4, kc = c2 & 15;
        float4 f0 = W4[row * 32 + kc * 2];
        float4 f1 = W4[row * 32 + kc * 2 + 1];
        int nt = row >> 4, colw = row & 15, kk = kc >> 2, qd = kc & 3;
        int a8 = (nt * 4 + kk) * 128 + SWZ(colw, qd) * 2;
        uint4 u;
        u.x = pk2(f0.x, f0.y); u.y = pk2(f0.z, f0.w);
        u.z = pk2(f1.x, f1.y); u.w = pk2(f1.z, f1.w);
        *(uint4*)&Wl[a8 * 4] = u;
    }

    const int wv = t >> 6, lane = t & 63;
    const int col = lane & 15, quad = lane >> 4;

    // per-thread piece coords for pack / weighted-sum
    const int u = t & 31, rg = t >> 5;
    const int ukk = u >> 3, uqd = (u >> 1) & 3, uh = u & 1;

    const float4* base = (const float4*)(ctx + ((size_t)b * SS + (size_t)chunk * CHROWS) * DD);

    float4 R[8];
    uint2 P[8];
    // pack R -> Cl[buf] at this thread's 8 (row, piece) slots; keep pairs in P
    auto pack_tile = [&](int buf) {
#pragma unroll
        for (int i = 0; i < 8; i++) {
            int row = rg + 8 * i, w = row >> 4, c = row & 15;
            int a8 = (w * 4 + ukk) * 128 + SWZ(c, uqd) * 2 + uh;
            uint2 pk;
            pk.x = pk2(R[i].x, R[i].y);
            pk.y = pk2(R[i].z, R[i].w);
            P[i] = pk;
            *(uint2*)&Cl[buf][a8 * 4] = pk;
        }
    };

    // issue tile-0 loads; their latency hides under the q matvec below
#pragma unroll
    for (int i = 0; i < 8; i++) R[i] = base[t + 256 * i];

    __syncthreads();  // xin visible

    // ---- prologue phase 2: q = tanh(input @ W_dec^T + b_dec), inline.
    // Identical FP op order to the old qproj kernel -> bit-identical q.
    if (t < DD) {
        const float4* wrow = (const float4*)(W_dec + (size_t)t * DD);
        float acc = 0.f;
#pragma unroll
        for (int k4 = 0; k4 < DD / 4; k4++) {
            float4 w = wrow[k4];
            float4 x = ((const float4*)xin)[k4];
            acc += w.x * x.x + w.y * x.y + w.z * x.z + w.w * x.w;
        }
        float qs = tanh_fast(acc + b_dec[t]);
        qsh[t] = qs;
        if (chunk == 0) q[b * DD + t] = qs;  // for K3
    }
    pack_tile(0);     // counted vmcnt wait on R (issued well before)
    __syncthreads();  // qsh + Cl[0] + Wl visible

    float qv[8], bv[8];
#pragma unroll
    for (int nt = 0; nt < 8; nt++) {
        qv[nt] = qsh[nt * 16 + col];
        bv[nt] = b_enc[nt * 16 + col];
    }

    float Mrun = -INFINITY, Trun = 0.f;
    float4 acc4 = {0.f, 0.f, 0.f, 0.f};

    for (int it = 0; it < NTILE; ++it) {
        const int cur = it & 1;
        // issue next-tile loads; they stay in flight across BOTH barriers
        if (it < NTILE - 1) {
            const float4* tb = base + (size_t)(it + 1) * 2048;
#pragma unroll
            for (int i = 0; i < 8; i++) R[i] = tb[t + 256 * i];
        }

        // ---- MFMA from swizzled Cl[cur] / Wl (proven compute shape)
        bf16x8 a[4];
#pragma unroll
        for (int kk = 0; kk < 4; kk++) {
            int a8 = (wv * 4 + kk) * 128 + SWZ(col, quad) * 2;
            a[kk] = *(const bf16x8*)&Cl[cur][a8 * 4];
        }
        f32x4 acc[8];
#pragma unroll
        for (int nt = 0; nt < 8; nt++) {
            f32x4 c = {0.f, 0.f, 0.f, 0.f};
#pragma unroll
            for (int kk = 0; kk < 4; kk++) {
                int a8 = (nt * 4 + kk) * 128 + SWZ(col, quad) * 2;
                bf16x8 bf = *(const bf16x8*)&Wl[a8 * 4];
                c = __builtin_amdgcn_mfma_f32_16x16x32_bf16(a[kk], bf, c, 0, 0, 0);
            }
            acc[nt] = c;
        }

        // ---- epilogue: tanh, dot q, col-reduce, write sw + raw scores
#pragma unroll
        for (int r = 0; r < 4; r++) {
            float v = 0.f;
#pragma unroll
            for (int nt = 0; nt < 8; nt++)
                v += tanh_fast(acc[nt][r] + bv[nt]) * qv[nt];
            v += __shfl_xor(v, 1);
            v += __shfl_xor(v, 2);
            v += __shfl_xor(v, 4);
            v += __shfl_xor(v, 8);
            if (col == 0) {
                int lrow = wv * 16 + quad * 4 + r;
                sw[lrow] = v;
                scores[(size_t)b * SS + (size_t)chunk * CHROWS + it * 64 + lrow] = v;
            }
        }
        lds_barrier();  // A: sw visible; Cl[cur] frag reads done
                        // (global loads for tile it+1 remain in flight)

        // ---- per-wave (redundant) online softmax over this tile's 64 rows
        float sv = sw[lane];
        float m = sv;
#pragma unroll
        for (int off = 1; off < 64; off <<= 1) m = fmaxf(m, __shfl_xor(m, off));
        float Mnew = fmaxf(Mrun, m);
        float alpha = __expf(Mrun - Mnew);
        float wlane = __expf(sv - Mnew);
        float ts = wlane;
#pragma unroll
        for (int off = 1; off < 64; off <<= 1) ts += __shfl_xor(ts, off);
        Trun = Trun * alpha + ts;
        Mrun = Mnew;

        // ---- weighted ctx accumulation from pack-time registers (tile it)
        acc4.x *= alpha; acc4.y *= alpha; acc4.z *= alpha; acc4.w *= alpha;
#pragma unroll
        for (int i = 0; i < 8; i++) {
            int row = rg + 8 * i;
            uint2 pk = P[i];
            float wi = __shfl(wlane, row);
            acc4.x += wi * bflo(pk.x);
            acc4.y += wi * bfhi(pk.x);
            acc4.z += wi * bflo(pk.y);
            acc4.w += wi * bfhi(pk.y);
        }

        // pack the prefetched tile into the OTHER buffer (counted vmcnt here)
        if (it < NTILE - 1) pack_tile(cur ^ 1);

        lds_barrier();  // B: Cl[cur^1] ready; sw reads done
    }

    // ---- block reduce: thread t holds dims [4u,4u+4) over row-group rg
    red[t] = acc4;
    __syncthreads();
    if (t < 32) {
        float4 s = red[t];
#pragma unroll
        for (int k = 1; k < 8; k++) {
            float4 p = red[t + 32 * k];
            s.x += p.x; s.y += p.y; s.z += p.z; s.w += p.w;
        }
        *(float4*)&wcp[(size_t)blockIdx.x * DD + 4 * t] = s;
    }
    if (t == 0) {
        Mp[blockIdx.x] = Mrun;
        Tp[blockIdx.x] = Trun;
    }
}

// ---------------- K3: combine 8 per-block partials per batch + fused out proj
__global__ void combine_out_kernel(const float* __restrict__ wcp,
                                   const float* __restrict__ Mp,
                                   const float* __restrict__ Tp,
                                   const float* __restrict__ q,
                                   const float* __restrict__ W_out,
                                   float* __restrict__ h) {
    __shared__ float cat[2 * DD];
    const int b = blockIdx.x, d = threadIdx.x;  // 128 threads
    float M = -INFINITY;
#pragma unroll
    for (int j = 0; j < NCHUNK; j++) M = fmaxf(M, Mp[b * NCHUNK + j]);
    float T = 0.f, acc = 0.f;
#pragma unroll
    for (int j = 0; j < NCHUNK; j++) {
        float e = __expf(Mp[b * NCHUNK + j] - M);
        T += Tp[b * NCHUNK + j] * e;
        acc += wcp[(size_t)(b * NCHUNK + j) * DD + d] * e;
    }
    float ti = 1.f / T;
    cat[d] = acc * ti;          // weighted_context
    cat[DD + d] = q[b * DD + d];
    __syncthreads();
    const float4* wrow = (const float4*)(W_out + (size_t)d * 2 * DD);
    float a2 = 0.f;
#pragma unroll
    for (int k4 = 0; k4 < 2 * DD / 4; k4++) {
        float4 w = wrow[k4];
        float4 x = ((const float4*)cat)[k4];
        a2 += w.x * x.x + w.y * x.y + w.z * x.z + w.w * x.w;
    }
    h[b * DD + d] = tanh_fast(a2);
}

// ---------------- K4: attn = exp(scores - M)/T  (M,T recomputed inline from
// Mp/Tp with K3's exact op order -> bit-identical; no dependency on K3)
__global__ __launch_bounds__(512) void attnfin_kernel(const float* __restrict__ scores,
                                                      const float* __restrict__ Mp,
                                                      const float* __restrict__ Tp,
                                                      float* __restrict__ attn) {
    const int b = blockIdx.x >> 2, seg = blockIdx.x & 3;
    float M = -INFINITY;
#pragma unroll
    for (int j = 0; j < NCHUNK; j++) M = fmaxf(M, Mp[b * NCHUNK + j]);
    float T = 0.f;
#pragma unroll
    for (int j = 0; j < NCHUNK; j++) T += Tp[b * NCHUNK + j] * __expf(Mp[b * NCHUNK + j] - M);
    const float ti = 1.f / T;
    const float4* s4 = (const float4*)(scores + (size_t)b * SS) + seg * 512;
    float4* a4 = (float4*)(attn + (size_t)b * SS) + seg * 512;
    float4 v = s4[threadIdx.x];
    v.x = __expf(v.x - M) * ti;
    v.y = __expf(v.y - M) * ti;
    v.z = __expf(v.z - M) * ti;
    v.w = __expf(v.w - M) * ti;
    a4[threadIdx.x] = v;
}

extern "C" void kernel_launch(void* const* d_in, const int* in_sizes, int n_in,
                              void* d_out, int out_size, void* d_ws, size_t ws_size,
                              hipStream_t stream) {
    const float* input = (const float*)d_in[0];
    const float* ctx   = (const float*)d_in[1];
    const float* W_enc = (const float*)d_in[2];
    const float* b_enc = (const float*)d_in[3];
    const float* W_dec = (const float*)d_in[4];
    const float* b_dec = (const float*)d_in[5];
    const float* W_out = (const float*)d_in[6];

    float* h    = (float*)d_out;            // [B, D]
    float* attn = (float*)d_out + BB * DD;  // [B, S]

    float* ws     = (float*)d_ws;
    float* q      = ws;                       // 8192
    float* scores = ws + 8192;                // 524288 raw scores
    float* wcp    = scores + 524288;          // 512*128 partials
    float* Mp     = wcp + 512 * DD;           // 512
    float* Tp     = Mp + 512;                 // 512

    score_fused_kernel<<<BB * NCHUNK, 256, 0, stream>>>(ctx, W_enc, b_enc,
                                                        input, W_dec, b_dec,
                                                        q, scores, wcp, Mp, Tp);
    attnfin_kernel<<<BB * 4, 512, 0, stream>>>(scores, Mp, Tp, attn);
    combine_out_kernel<<<BB, DD, 0, stream>>>(wcp, Mp, Tp, q, W_out, h);
}

// Round 10
// 398.925 us; speedup vs baseline: 1.0519x; 1.0075x over previous
//
#include <hip/hip_runtime.h>
#include <hip/hip_bf16.h>

#define BB 64
#define SS 8192
#define DD 128
#define NCHUNK 8    // chunks per batch
#define CHROWS 1024 // rows per chunk
#define NTILE 16    // 64-row tiles per chunk

typedef __attribute__((ext_vector_type(8))) short bf16x8;
typedef __attribute__((ext_vector_type(4))) float f32x4;

// swizzled slot within a (w,kk) 128-slot region; 8-byte units
#define SWZ(c, qd) ((qd) * 16 + ((c) ^ (2 * (qd))))

__device__ __forceinline__ unsigned pk2(float x, float y) {
    __hip_bfloat162 h = __float22bfloat162_rn(make_float2(x, y));
    union { __hip_bfloat162 h2; unsigned u; } cv;
    cv.h2 = h;
    return cv.u;
}

__device__ __forceinline__ float bflo(unsigned p) { return __uint_as_float(p << 16); }
__device__ __forceinline__ float bfhi(unsigned p) { return __uint_as_float(p & 0xffff0000u); }

__device__ __forceinline__ float tanh_fast(float x) {
    float e = __expf(2.f * x);
    return 1.f - 2.f / (e + 1.f);
}

// LDS-visibility barrier that does NOT drain outstanding global loads
// (unlike __syncthreads, which forces s_waitcnt vmcnt(0) before s_barrier).
__device__ __forceinline__ void lds_barrier() {
    asm volatile("s_waitcnt lgkmcnt(0)" ::: "memory");
    __builtin_amdgcn_s_barrier();
    asm volatile("" ::: "memory");
}

// ---------------- K1: q = tanh(input @ W_dec^T + b_dec)
__global__ void qproj_kernel(const float* __restrict__ input,
                             const float* __restrict__ W_dec,
                             const float* __restrict__ b_dec,
                             float* __restrict__ q) {
    __shared__ float xin[DD];
    const int b = blockIdx.x, d = threadIdx.x;  // 128 threads
    xin[d] = input[b * DD + d];
    __syncthreads();
    const float4* wrow = (const float4*)(W_dec + (size_t)d * DD);
    float acc = 0.f;
#pragma unroll
    for (int k4 = 0; k4 < DD / 4; k4++) {
        float4 w = wrow[k4];
        float4 x = ((const float4*)xin)[k4];
        acc += w.x * x.x + w.y * x.y + w.z * x.z + w.w * x.w;
    }
    q[b * DD + d] = tanh_fast(acc + b_dec[d]);
}

// ---------------- K2: fused scores + online softmax + weighted ctx sum
// R6 interior with ONE barrier per tile: pack(t+1) moved BEFORE the
// barrier (into tile t's compute phase). Hazards: pack(t+1, other buf)
// pre-barrier -> frag-reads(t+1) post-barrier; sw double-buffered;
// Cl rewrite(t+2) is post-barrier(t+1) > all reads(t). P double-buffered
// (PA/PB) since wsum(t) now runs after pack(t+1).
__global__ __launch_bounds__(256, 2) void score_fused_kernel(
    const float* __restrict__ ctx,
    const float* __restrict__ W_enc,
    const float* __restrict__ b_enc,
    const float* __restrict__ q,
    float* __restrict__ scores,
    float* __restrict__ wcp,   // [512][128]
    float* __restrict__ Mp,    // [512]
    float* __restrict__ Tp) {  // [512]
    __shared__ __align__(16) short Wl[16384];     // 32 KB fragment-order W_enc
    __shared__ __align__(16) short Cl[2][8192];   // 2 x 16 KB swizzled bf16 ctx tile
    __shared__ float sw[2][64];                   // double-buffered row scores
    __shared__ float4 red[256];

    const int t = threadIdx.x;

    // ---- stage W_enc: region (nt*4+kk), slot SWZ(col,qd), halves h=0/1
    const float4* W4 = (const float4*)W_enc;
    for (int c2 = t; c2 < 2048; c2 += 256) {
        int row = c2 >> 4, kc = c2 & 15;
        float4 f0 = W4[row * 32 + kc * 2];
        float4 f1 = W4[row * 32 + kc * 2 + 1];
        int nt = row >> 4, colw = row & 15, kk = kc >> 2, qd = kc & 3;
        int a8 = (nt * 4 + kk) * 128 + SWZ(colw, qd) * 2;
        uint4 u;
        u.x = pk2(f0.x, f0.y); u.y = pk2(f0.z, f0.w);
        u.z = pk2(f1.x, f1.y); u.w = pk2(f1.z, f1.w);
        *(uint4*)&Wl[a8 * 4] = u;
    }

    const int wv = t >> 6, lane = t & 63;
    const int col = lane & 15, quad = lane >> 4;
    const int b = blockIdx.x >> 3;
    const int chunk = blockIdx.x & 7;

    // per-thread piece coords for pack / weighted-sum
    const int u = t & 31, rg = t >> 5;
    const int ukk = u >> 3, uqd = (u >> 1) & 3, uh = u & 1;

    float qv[8], bv[8];
#pragma unroll
    for (int nt = 0; nt < 8; nt++) {
        qv[nt] = q[b * DD + nt * 16 + col];
        bv[nt] = b_enc[nt * 16 + col];
    }

    const float4* base = (const float4*)(ctx + ((size_t)b * SS + (size_t)chunk * CHROWS) * DD);

    float4 R[8];
    uint2 PA[8], PB[8];
    float Mrun = -INFINITY, Trun = 0.f;
    float4 acc4 = {0.f, 0.f, 0.f, 0.f};

// issue tile's global loads into R (8 x dwordx4, coalesced)
#define ISSUE(tile) do {                                             \
    const float4* tb_ = base + (size_t)(tile) * 2048;                \
    _Pragma("unroll")                                                \
    for (int i = 0; i < 8; i++) R[i] = tb_[t + 256 * i];             \
} while (0)

// pack R into Cl[buf]; keep bf16 pairs in P (counted vmcnt wait on R here)
#define PACK(buf, P) do {                                            \
    _Pragma("unroll")                                                \
    for (int i = 0; i < 8; i++) {                                    \
        int row_ = rg + 8 * i, w_ = row_ >> 4, c_ = row_ & 15;       \
        int a8_ = (w_ * 4 + ukk) * 128 + SWZ(c_, uqd) * 2 + uh;      \
        uint2 pk_;                                                   \
        pk_.x = pk2(R[i].x, R[i].y);                                 \
        pk_.y = pk2(R[i].z, R[i].w);                                 \
        P[i] = pk_;                                                  \
        *(uint2*)&Cl[buf][a8_ * 4] = pk_;                            \
    }                                                                \
} while (0)

// MFMA + tanh/dot epilogue + sw/scores write (proven compute shape)
#define COMPUTE(it, cur, swb) do {                                   \
    bf16x8 a_[4];                                                    \
    _Pragma("unroll")                                                \
    for (int kk = 0; kk < 4; kk++) {                                 \
        int a8_ = (wv * 4 + kk) * 128 + SWZ(col, quad) * 2;          \
        a_[kk] = *(const bf16x8*)&Cl[cur][a8_ * 4];                  \
    }                                                                \
    f32x4 acc_[8];                                                   \
    _Pragma("unroll")                                                \
    for (int nt = 0; nt < 8; nt++) {                                 \
        f32x4 c_ = {0.f, 0.f, 0.f, 0.f};                             \
        _Pragma("unroll")                                            \
        for (int kk = 0; kk < 4; kk++) {                             \
            int a8_ = (nt * 4 + kk) * 128 + SWZ(col, quad) * 2;      \
            bf16x8 bf_ = *(const bf16x8*)&Wl[a8_ * 4];               \
            c_ = __builtin_amdgcn_mfma_f32_16x16x32_bf16(a_[kk], bf_, c_, 0, 0, 0); \
        }                                                            \
        acc_[nt] = c_;                                               \
    }                                                                \
    _Pragma("unroll")                                                \
    for (int r = 0; r < 4; r++) {                                    \
        float v_ = 0.f;                                              \
        _Pragma("unroll")                                            \
        for (int nt = 0; nt < 8; nt++)                               \
            v_ += tanh_fast(acc_[nt][r] + bv[nt]) * qv[nt];          \
        v_ += __shfl_xor(v_, 1);                                     \
        v_ += __shfl_xor(v_, 2);                                     \
        v_ += __shfl_xor(v_, 4);                                     \
        v_ += __shfl_xor(v_, 8);                                     \
        if (col == 0) {                                              \
            int lrow_ = wv * 16 + quad * 4 + r;                      \
            sw[swb][lrow_] = v_;                                     \
            scores[(size_t)b * SS + (size_t)chunk * CHROWS + (it) * 64 + lrow_] = v_; \
        }                                                            \
    }                                                                \
} while (0)

// online softmax over 64 rows + weighted ctx accumulation from P
#define SMWSUM(P, swb) do {                                          \
    float sv_ = sw[swb][lane];                                       \
    float m_ = sv_;                                                  \
    _Pragma("unroll")                                                \
    for (int off = 1; off < 64; off <<= 1) m_ = fmaxf(m_, __shfl_xor(m_, off)); \
    float Mn_ = fmaxf(Mrun, m_);                                     \
    float al_ = __expf(Mrun - Mn_);                                  \
    float wl_ = __expf(sv_ - Mn_);                                   \
    float ts_ = wl_;                                                 \
    _Pragma("unroll")                                                \
    for (int off = 1; off < 64; off <<= 1) ts_ += __shfl_xor(ts_, off); \
    Trun = Trun * al_ + ts_;                                         \
    Mrun = Mn_;                                                      \
    acc4.x *= al_; acc4.y *= al_; acc4.z *= al_; acc4.w *= al_;      \
    _Pragma("unroll")                                                \
    for (int i = 0; i < 8; i++) {                                    \
        int row_ = rg + 8 * i;                                       \
        uint2 pk_ = P[i];                                            \
        float wi_ = __shfl(wl_, row_);                               \
        acc4.x += wi_ * bflo(pk_.x);                                 \
        acc4.y += wi_ * bfhi(pk_.x);                                 \
        acc4.z += wi_ * bflo(pk_.y);                                 \
        acc4.w += wi_ * bfhi(pk_.y);                                 \
    }                                                                \
} while (0)

    // prologue: tile 0 -> Cl[0], PA
    ISSUE(0);
    PACK(0, PA);
    __syncthreads();  // Wl + Cl[0] visible

    for (int it2 = 0; it2 < NTILE / 2; ++it2) {
        const int T = 2 * it2;

        // ---- even tile T: read Cl[0]/sw0; stage T+1 -> Cl[1],PB pre-barrier
        ISSUE(T + 1);
        COMPUTE(T, 0, 0);
        PACK(1, PB);
        lds_barrier();     // covers: pack(T+1)->reads(T+1), sw0 w->r,
                           // reads(T) -> pack(T+2) [post-barrier next phase]
        SMWSUM(PA, 0);     // consumes tile T

        // ---- odd tile T+1: read Cl[1]/sw1; stage T+2 -> Cl[0],PA
        if (T + 2 < NTILE) ISSUE(T + 2);
        COMPUTE(T + 1, 1, 1);
        if (T + 2 < NTILE) PACK(0, PA);
        lds_barrier();
        SMWSUM(PB, 1);     // consumes tile T+1
    }

    // ---- block reduce: thread t holds dims [4u,4u+4) over row-group rg
    red[t] = acc4;
    __syncthreads();
    if (t < 32) {
        float4 s = red[t];
#pragma unroll
        for (int k = 1; k < 8; k++) {
            float4 p = red[t + 32 * k];
            s.x += p.x; s.y += p.y; s.z += p.z; s.w += p.w;
        }
        *(float4*)&wcp[(size_t)blockIdx.x * DD + 4 * t] = s;
    }
    if (t == 0) {
        Mp[blockIdx.x] = Mrun;
        Tp[blockIdx.x] = Trun;
    }
}

// ---------------- K3: combine 8 per-block partials per batch + fused out proj
__global__ void combine_out_kernel(const float* __restrict__ wcp,
                                   const float* __restrict__ Mp,
                                   const float* __restrict__ Tp,
                                   const float* __restrict__ q,
                                   const float* __restrict__ W_out,
                                   float* __restrict__ h,
                                   float* __restrict__ Ms,
                                   float* __restrict__ Tinv) {
    __shared__ float cat[2 * DD];
    const int b = blockIdx.x, d = threadIdx.x;  // 128 threads
    float M = -INFINITY;
#pragma unroll
    for (int j = 0; j < NCHUNK; j++) M = fmaxf(M, Mp[b * NCHUNK + j]);
    float T = 0.f, acc = 0.f;
#pragma unroll
    for (int j = 0; j < NCHUNK; j++) {
        float e = __expf(Mp[b * NCHUNK + j] - M);
        T += Tp[b * NCHUNK + j] * e;
        acc += wcp[(size_t)(b * NCHUNK + j) * DD + d] * e;
    }
    float ti = 1.f / T;
    cat[d] = acc * ti;          // weighted_context
    cat[DD + d] = q[b * DD + d];
    if (d == 0) { Ms[b] = M; Tinv[b] = ti; }
    __syncthreads();
    const float4* wrow = (const float4*)(W_out + (size_t)d * 2 * DD);
    float a2 = 0.f;
#pragma unroll
    for (int k4 = 0; k4 < 2 * DD / 4; k4++) {
        float4 w = wrow[k4];
        float4 x = ((const float4*)cat)[k4];
        a2 += w.x * x.x + w.y * x.y + w.z * x.z + w.w * x.w;
    }
    h[b * DD + d] = tanh_fast(a2);
}

// ---------------- K4: attn = exp(scores - M)/T
__global__ __launch_bounds__(512) void attnfin_kernel(const float* __restrict__ scores,
                                                      const float* __restrict__ Ms,
                                                      const float* __restrict__ Tinv,
                                                      float* __restrict__ attn) {
    const int b = blockIdx.x >> 2, seg = blockIdx.x & 3;
    const float M = Ms[b], ti = Tinv[b];
    const float4* s4 = (const float4*)(scores + (size_t)b * SS) + seg * 512;
    float4* a4 = (float4*)(attn + (size_t)b * SS) + seg * 512;
    float4 v = s4[threadIdx.x];
    v.x = __expf(v.x - M) * ti;
    v.y = __expf(v.y - M) * ti;
    v.z = __expf(v.z - M) * ti;
    v.w = __expf(v.w - M) * ti;
    a4[threadIdx.x] = v;
}

extern "C" void kernel_launch(void* const* d_in, const int* in_sizes, int n_in,
                              void* d_out, int out_size, void* d_ws, size_t ws_size,
                              hipStream_t stream) {
    const float* input = (const float*)d_in[0];
    const float* ctx   = (const float*)d_in[1];
    const float* W_enc = (const float*)d_in[2];
    const float* b_enc = (const float*)d_in[3];
    const float* W_dec = (const float*)d_in[4];
    const float* b_dec = (const float*)d_in[5];
    const float* W_out = (const float*)d_in[6];

    float* h    = (float*)d_out;            // [B, D]
    float* attn = (float*)d_out + BB * DD;  // [B, S]

    float* ws     = (float*)d_ws;
    float* q      = ws;                       // 8192
    float* scores = ws + 8192;                // 524288 raw scores
    float* wcp    = scores + 524288;          // 512*128 partials
    float* Mp     = wcp + 512 * DD;           // 512
    float* Tp     = Mp + 512;                 // 512
    float* Ms     = Tp + 512;                 // 64
    float* Tinv   = Ms + 64;                  // 64

    qproj_kernel<<<BB, DD, 0, stream>>>(input, W_dec, b_dec, q);
    score_fused_kernel<<<BB * NCHUNK, 256, 0, stream>>>(ctx, W_enc, b_enc, q,
                                                        scores, wcp, Mp, Tp);
    combine_out_kernel<<<BB, DD, 0, stream>>>(wcp, Mp, Tp, q, W_out, h, Ms, Tinv);
    attnfin_kernel<<<BB * 4, 512, 0, stream>>>(scores, Ms, Tinv, attn);
}